// Round 1
// baseline (1540.574 us; speedup 1.0000x reference)
//
#include <hip/hip_runtime.h>
#include <math.h>

#define HID 128
#define EPS 1e-5f

// ---------------- graph preprocessing ----------------

__global__ void k_count_deg(const int* __restrict__ dst, int* __restrict__ degc, int e) {
    int i = blockIdx.x * 256 + threadIdx.x;
    if (i < e) atomicAdd(&degc[dst[i]], 1);
}

__global__ void k_dinv(const int* __restrict__ degc, float* __restrict__ dinv, int n) {
    int i = blockIdx.x * 256 + threadIdx.x;
    if (i < n) dinv[i] = rsqrtf((float)(degc[i] + 1));  // +1 self-loop; deg>=1 always
}

// single-block exclusive scan of degc -> offs (N ~ 1e5, one block of 1024 threads)
__global__ void k_scan(const int* __restrict__ counts, int* __restrict__ offs, int n) {
    __shared__ int lds[1024];
    int tid = threadIdx.x;
    int chunk = (n + 1023) >> 10;
    int start = tid * chunk;
    int end = min(start + chunk, n);
    int s = 0;
    for (int i = start; i < end; ++i) s += counts[i];
    lds[tid] = s;
    __syncthreads();
    for (int off = 1; off < 1024; off <<= 1) {
        int v = (tid >= off) ? lds[tid - off] : 0;
        __syncthreads();
        lds[tid] += v;
        __syncthreads();
    }
    int prefix = (tid == 0) ? 0 : lds[tid - 1];
    for (int i = start; i < end; ++i) { offs[i] = prefix; prefix += counts[i]; }
    if (tid == 1023) offs[n] = prefix;  // == E (threads past n have empty ranges, lds carries total)
}

__global__ void k_copy(const int* __restrict__ a, int* __restrict__ b, int n) {
    int i = blockIdx.x * 256 + threadIdx.x;
    if (i < n) b[i] = a[i];
}

__global__ void k_fill(const int* __restrict__ src, const int* __restrict__ dst,
                       int* __restrict__ cursor, int* __restrict__ csr, int e) {
    int i = blockIdx.x * 256 + threadIdx.x;
    if (i < e) {
        int d = dst[i];
        int pos = atomicAdd(&cursor[d], 1);
        csr[pos] = src[i];
    }
}

// ---------------- embed: h = relu(x @ We + be), x is [N,2] ----------------

__global__ void k_embed(const float* __restrict__ x, const float* __restrict__ We,
                        const float* __restrict__ be, float* __restrict__ h, int n) {
    int i = blockIdx.x * 256 + threadIdx.x;
    if (i >= n * HID) return;
    int node = i >> 7, j = i & 127;
    float v = x[2 * node] * We[j] + x[2 * node + 1] * We[HID + j] + be[j];
    h[i] = fmaxf(v, 0.f);
}

// ---------------- GEMM: t[n][j] = sum_k h[n][k] * W[k][j], 128x128 ----------------
// 64 nodes/block, 256 threads, thread tile 4 nodes x 4 feats, 2 feature chunks of 64.

__global__ __launch_bounds__(256) void k_gemm128(const float* __restrict__ h, const float* __restrict__ W,
                                                 float* __restrict__ out, int n) {
    __shared__ float hs[128][66];   // transposed h tile: hs[k][node], pad 66 to spread staging banks
    __shared__ float ws[128][64];   // W feature chunk
    int tid = threadIdx.x;
    int nb = blockIdx.x * 64;
    const float4* h4 = (const float4*)h;
#pragma unroll
    for (int r = 0; r < 8; ++r) {
        int idx = r * 256 + tid;           // 0..2047
        int ni = idx >> 5;                 // node within tile
        int k4 = idx & 31;                 // float4 index along k
        int node = nb + ni;
        float4 v = make_float4(0.f, 0.f, 0.f, 0.f);
        if (node < n) v = h4[(size_t)node * 32 + k4];
        hs[k4 * 4 + 0][ni] = v.x; hs[k4 * 4 + 1][ni] = v.y;
        hs[k4 * 4 + 2][ni] = v.z; hs[k4 * 4 + 3][ni] = v.w;
    }
    int fg = tid & 15, ng = tid >> 4;
    const float4* w4 = (const float4*)W;
    for (int c = 0; c < 2; ++c) {
        if (c) __syncthreads();
#pragma unroll
        for (int r = 0; r < 8; ++r) {
            int idx = r * 256 + tid;       // 0..2047
            int k = idx >> 4, f4 = idx & 15;
            *((float4*)&ws[k][f4 * 4]) = w4[k * 32 + c * 16 + f4];
        }
        __syncthreads();
        float acc[4][4] = {{0.f}};
#pragma unroll 8
        for (int k = 0; k < 128; ++k) {
            float2 a0 = *((const float2*)&hs[k][ng * 4]);
            float2 a1 = *((const float2*)&hs[k][ng * 4 + 2]);
            float4 w = *((const float4*)&ws[k][fg * 4]);
            float av[4] = {a0.x, a0.y, a1.x, a1.y};
            float wv[4] = {w.x, w.y, w.z, w.w};
#pragma unroll
            for (int i = 0; i < 4; ++i)
#pragma unroll
                for (int j = 0; j < 4; ++j)
                    acc[i][j] += av[i] * wv[j];
        }
#pragma unroll
        for (int i = 0; i < 4; ++i) {
            int node = nb + ng * 4 + i;
            if (node < n)
                *((float4*)&out[(size_t)node * 128 + c * 64 + fg * 4]) =
                    make_float4(acc[i][0], acc[i][1], acc[i][2], acc[i][3]);
        }
    }
}

// ---------------- aggregation: out[i] = dinv[i]*(sum_{s in N(i)} dinv[s]*t[s] + dinv[i]*t[i]) + b ---
// one wave per node; lane holds a float2 of features (64 lanes x 2 = 128)

__global__ __launch_bounds__(256) void k_agg(const float* __restrict__ t, const int* __restrict__ offs,
                                             const int* __restrict__ csr, const float* __restrict__ dinv,
                                             const float* __restrict__ bias, float* __restrict__ out, int n) {
    int lane = threadIdx.x & 63;
    int node = blockIdx.x * 4 + (threadIdx.x >> 6);
    if (node >= n) return;
    const float2* t2 = (const float2*)t;
    float di = dinv[node];
    float2 v = t2[(size_t)node * 64 + lane];
    float ax = v.x * di, ay = v.y * di;   // self-loop (final *di gives dinv^2)
    int e0 = offs[node], e1 = offs[node + 1];
    for (int e = e0; e < e1; ++e) {
        int s = csr[e];
        float ds = dinv[s];
        float2 u = t2[(size_t)s * 64 + lane];
        ax += u.x * ds; ay += u.y * ds;
    }
    float2 b = ((const float2*)bias)[lane];
    float2 o = make_float2(ax * di + b.x, ay * di + b.y);
    ((float2*)out)[(size_t)node * 64 + lane] = o;
}

// ---------------- BN ----------------

__global__ void k_bn_stats128(const float* __restrict__ v, float* __restrict__ S,
                              float* __restrict__ SS, int n) {
    int j = threadIdx.x;  // 128 threads
    int per = (n + gridDim.x - 1) / gridDim.x;
    int start = blockIdx.x * per;
    int end = min(start + per, n);
    float s = 0.f, ss = 0.f;
    for (int i = start; i < end; ++i) {
        float x = v[(size_t)i * 128 + j];
        s += x; ss += x * x;
    }
    atomicAdd(&S[j], s);
    atomicAdd(&SS[j], ss);
}

__global__ void k_bn_stats32(const float* __restrict__ v, float* __restrict__ S,
                             float* __restrict__ SS, int n) {
    int j = threadIdx.x & 31, sub = threadIdx.x >> 5;  // 128 threads = 4 node-subsets
    int per = (n + gridDim.x - 1) / gridDim.x;
    int start = blockIdx.x * per;
    int end = min(start + per, n);
    float s = 0.f, ss = 0.f;
    for (int i = start + sub; i < end; i += 4) {
        float x = v[(size_t)i * 32 + j];
        s += x; ss += x * x;
    }
    atomicAdd(&S[j], s);
    atomicAdd(&SS[j], ss);
}

__global__ void k_bn_finalize(const float* __restrict__ S, const float* __restrict__ SS,
                              const float* __restrict__ g, const float* __restrict__ bt,
                              float* __restrict__ A, float* __restrict__ C, int n, int hid) {
    int j = threadIdx.x;
    if (j >= hid) return;
    float mu = S[j] / (float)n;
    float var = SS[j] / (float)n - mu * mu;
    float inv = rsqrtf(var + EPS);
    A[j] = g[j] * inv;
    C[j] = bt[j] - mu * g[j] * inv;
}

// h[i] = relu(agg[i]*A + C) + h[i]
__global__ void k_bn_apply_res(const float* __restrict__ agg, const float* __restrict__ A,
                               const float* __restrict__ C, float* __restrict__ h, int total) {
    int i = blockIdx.x * 256 + threadIdx.x;
    if (i < total) {
        int j = i & 127;
        float v = agg[i] * A[j] + C[j];
        h[i] += fmaxf(v, 0.f);
    }
}

// ---------------- head GEMM: tf = h @ Wf1 + bf1 (128 -> 32) ----------------
// 64 nodes/block, 256 threads, thread tile 2 nodes x 4 feats

__global__ __launch_bounds__(256) void k_gemmf(const float* __restrict__ h, const float* __restrict__ W,
                                               const float* __restrict__ bias, float* __restrict__ out, int n) {
    __shared__ float hs[128][66];
    __shared__ float ws[128][32];
    int tid = threadIdx.x;
    int nb = blockIdx.x * 64;
    const float4* h4 = (const float4*)h;
#pragma unroll
    for (int r = 0; r < 8; ++r) {
        int idx = r * 256 + tid;
        int ni = idx >> 5, k4 = idx & 31;
        int node = nb + ni;
        float4 v = make_float4(0.f, 0.f, 0.f, 0.f);
        if (node < n) v = h4[(size_t)node * 32 + k4];
        hs[k4 * 4 + 0][ni] = v.x; hs[k4 * 4 + 1][ni] = v.y;
        hs[k4 * 4 + 2][ni] = v.z; hs[k4 * 4 + 3][ni] = v.w;
    }
    const float4* w4 = (const float4*)W;
#pragma unroll
    for (int r = 0; r < 4; ++r) {
        int idx = r * 256 + tid;   // 0..1023
        int k = idx >> 3, f4 = idx & 7;
        *((float4*)&ws[k][f4 * 4]) = w4[k * 8 + f4];
    }
    __syncthreads();
    int fg = tid & 7, ng = tid >> 3;  // ng 0..31 -> nodes ng*2, ng*2+1
    float acc[2][4] = {{0.f}};
#pragma unroll 8
    for (int k = 0; k < 128; ++k) {
        float2 a = *((const float2*)&hs[k][ng * 2]);
        float4 w = *((const float4*)&ws[k][fg * 4]);
        acc[0][0] += a.x * w.x; acc[0][1] += a.x * w.y; acc[0][2] += a.x * w.z; acc[0][3] += a.x * w.w;
        acc[1][0] += a.y * w.x; acc[1][1] += a.y * w.y; acc[1][2] += a.y * w.z; acc[1][3] += a.y * w.w;
    }
    float4 bb = *((const float4*)&bias[fg * 4]);
#pragma unroll
    for (int i = 0; i < 2; ++i) {
        int node = nb + ng * 2 + i;
        if (node < n)
            *((float4*)&out[(size_t)node * 32 + fg * 4]) =
                make_float4(acc[i][0] + bb.x, acc[i][1] + bb.y, acc[i][2] + bb.z, acc[i][3] + bb.w);
    }
}

// ---------------- final: out = tanh(relu(bn(tf)) @ Wf2 + bf2) ----------------

__global__ void k_final(const float* __restrict__ tf, const float* __restrict__ A,
                        const float* __restrict__ C, const float* __restrict__ Wf2,
                        const float* __restrict__ bf2, float* __restrict__ out, int n) {
    int node = blockIdx.x * 256 + threadIdx.x;
    if (node >= n) return;
    float o0 = bf2[0], o1 = bf2[1];
    const float4* t4 = (const float4*)(tf + (size_t)node * 32);
#pragma unroll
    for (int q = 0; q < 8; ++q) {
        float4 v = t4[q];
        float vv[4] = {v.x, v.y, v.z, v.w};
#pragma unroll
        for (int r = 0; r < 4; ++r) {
            int j = q * 4 + r;
            float f = fmaxf(vv[r] * A[j] + C[j], 0.f);
            o0 += f * Wf2[2 * j];
            o1 += f * Wf2[2 * j + 1];
        }
    }
    out[2 * node] = tanhf(o0);
    out[2 * node + 1] = tanhf(o1);
}

// ---------------- launch ----------------

extern "C" void kernel_launch(void* const* d_in, const int* in_sizes, int n_in,
                              void* d_out, int out_size, void* d_ws, size_t ws_size,
                              hipStream_t stream) {
    const float* x   = (const float*)d_in[0];
    const int*   ei  = (const int*)d_in[1];
    const float* We  = (const float*)d_in[2];
    const float* be  = (const float*)d_in[3];
    const float* W1  = (const float*)d_in[4];
    const float* b1  = (const float*)d_in[5];
    const float* g1  = (const float*)d_in[6];
    const float* bt1 = (const float*)d_in[7];
    const float* W2  = (const float*)d_in[8];
    const float* b2  = (const float*)d_in[9];
    const float* g2  = (const float*)d_in[10];
    const float* bt2 = (const float*)d_in[11];
    const float* W3  = (const float*)d_in[12];
    const float* b3  = (const float*)d_in[13];
    const float* g3  = (const float*)d_in[14];
    const float* bt3 = (const float*)d_in[15];
    const float* Wf1 = (const float*)d_in[16];
    const float* bf1 = (const float*)d_in[17];
    const float* gf  = (const float*)d_in[18];
    const float* btf = (const float*)d_in[19];
    const float* Wf2 = (const float*)d_in[20];
    const float* bf2 = (const float*)d_in[21];
    float* out = (float*)d_out;

    const int n = in_sizes[0] / 2;      // x is [N,2]
    const int e = in_sizes[1] / 2;      // edge_index is [2,E]
    const int* srcp = ei;
    const int* dstp = ei + e;

    char* p = (char*)d_ws;
    auto alloc = [&](size_t bytes) { void* r = (void*)p; p += (bytes + 255) & ~(size_t)255; return r; };
    int*   degc   = (int*)alloc((size_t)n * 4);
    int*   offs   = (int*)alloc((size_t)(n + 1) * 4);
    int*   cursor = (int*)alloc((size_t)n * 4);
    int*   csr    = (int*)alloc((size_t)e * 4);
    float* dinv   = (float*)alloc((size_t)n * 4);
    float* h      = (float*)alloc((size_t)n * HID * 4);
    float* t      = (float*)alloc((size_t)n * HID * 4);
    float* agg    = (float*)alloc((size_t)n * HID * 4);
    float* bnS    = (float*)alloc(HID * 4);
    float* bnSS   = (float*)alloc(HID * 4);
    float* bnA    = (float*)alloc(HID * 4);
    float* bnC    = (float*)alloc(HID * 4);
    float* tf     = t;  // alias: t is dead by head stage

    hipMemsetAsync(degc, 0, (size_t)n * 4, stream);
    k_count_deg<<<(e + 255) / 256, 256, 0, stream>>>(dstp, degc, e);
    k_dinv<<<(n + 255) / 256, 256, 0, stream>>>(degc, dinv, n);
    k_scan<<<1, 1024, 0, stream>>>(degc, offs, n);
    k_copy<<<(n + 255) / 256, 256, 0, stream>>>(offs, cursor, n);
    k_fill<<<(e + 255) / 256, 256, 0, stream>>>(srcp, dstp, cursor, csr, e);
    k_embed<<<(n * HID + 255) / 256, 256, 0, stream>>>(x, We, be, h, n);

    const float* Wl[3]  = {W1, W2, W3};
    const float* bl[3]  = {b1, b2, b3};
    const float* gl[3]  = {g1, g2, g3};
    const float* btl[3] = {bt1, bt2, bt3};
    for (int L = 0; L < 3; ++L) {
        k_gemm128<<<(n + 63) / 64, 256, 0, stream>>>(h, Wl[L], t, n);
        k_agg<<<(n + 3) / 4, 256, 0, stream>>>(t, offs, csr, dinv, bl[L], agg, n);
        hipMemsetAsync(bnS, 0, HID * 4, stream);
        hipMemsetAsync(bnSS, 0, HID * 4, stream);
        k_bn_stats128<<<512, 128, 0, stream>>>(agg, bnS, bnSS, n);
        k_bn_finalize<<<1, 128, 0, stream>>>(bnS, bnSS, gl[L], btl[L], bnA, bnC, n, 128);
        k_bn_apply_res<<<(n * HID + 255) / 256, 256, 0, stream>>>(agg, bnA, bnC, h, n * HID);
    }

    k_gemmf<<<(n + 63) / 64, 256, 0, stream>>>(h, Wf1, bf1, tf, n);
    hipMemsetAsync(bnS, 0, 32 * 4, stream);
    hipMemsetAsync(bnSS, 0, 32 * 4, stream);
    k_bn_stats32<<<512, 128, 0, stream>>>(tf, bnS, bnSS, n);
    k_bn_finalize<<<1, 32, 0, stream>>>(bnS, bnSS, gf, btf, bnA, bnC, n, 32);
    k_final<<<(n + 255) / 256, 256, 0, stream>>>(tf, bnA, bnC, Wf2, bf2, out, n);
}

// Round 2
// 1386.986 us; speedup vs baseline: 1.1107x; 1.1107x over previous
//
#include <hip/hip_runtime.h>
#include <math.h>

#define HID 128
#define EPS 1e-5f

// ---------------- graph preprocessing ----------------

__global__ void k_count_deg(const int* __restrict__ dst, int* __restrict__ degc, int e) {
    int i = blockIdx.x * 256 + threadIdx.x;
    if (i < e) atomicAdd(&degc[dst[i]], 1);
}

__global__ void k_dinv(const int* __restrict__ degc, float* __restrict__ dinv, int n) {
    int i = blockIdx.x * 256 + threadIdx.x;
    if (i < n) dinv[i] = rsqrtf((float)(degc[i] + 1));  // +1 self-loop; deg>=1 always
}

// single-block exclusive scan of degc -> offs (N ~ 1e5, one block of 1024 threads)
__global__ void k_scan(const int* __restrict__ counts, int* __restrict__ offs, int n) {
    __shared__ int lds[1024];
    int tid = threadIdx.x;
    int chunk = (n + 1023) >> 10;
    int start = tid * chunk;
    int end = min(start + chunk, n);
    int s = 0;
    for (int i = start; i < end; ++i) s += counts[i];
    lds[tid] = s;
    __syncthreads();
    for (int off = 1; off < 1024; off <<= 1) {
        int v = (tid >= off) ? lds[tid - off] : 0;
        __syncthreads();
        lds[tid] += v;
        __syncthreads();
    }
    int prefix = (tid == 0) ? 0 : lds[tid - 1];
    for (int i = start; i < end; ++i) { offs[i] = prefix; prefix += counts[i]; }
    if (tid == 1023) offs[n] = prefix;
}

__global__ void k_copy(const int* __restrict__ a, int* __restrict__ b, int n) {
    int i = blockIdx.x * 256 + threadIdx.x;
    if (i < n) b[i] = a[i];
}

__global__ void k_fill(const int* __restrict__ src, const int* __restrict__ dst,
                       int* __restrict__ cursor, int* __restrict__ csr, int e) {
    int i = blockIdx.x * 256 + threadIdx.x;
    if (i < e) {
        int d = dst[i];
        int pos = atomicAdd(&cursor[d], 1);
        csr[pos] = src[i];
    }
}

// ---------------- embed: h = relu(x @ We + be), x is [N,2] ----------------

__global__ void k_embed(const float* __restrict__ x, const float* __restrict__ We,
                        const float* __restrict__ be, float* __restrict__ h, int n) {
    int i = blockIdx.x * 256 + threadIdx.x;
    if (i >= n * HID) return;
    int node = i >> 7, j = i & 127;
    float v = x[2 * node] * We[j] + x[2 * node + 1] * We[HID + j] + be[j];
    h[i] = fmaxf(v, 0.f);
}

// ---------------- GEMM: t'[n][j] = dinv[n] * sum_k h[n][k] * W[k][j], 128x128 ---------
// dinv pre-fold: aggregation then only sums rows (removes per-edge dinv load).

__global__ __launch_bounds__(256) void k_gemm128(const float* __restrict__ h, const float* __restrict__ W,
                                                 const float* __restrict__ dinv,
                                                 float* __restrict__ out, int n) {
    __shared__ float hs[128][66];   // transposed h tile: hs[k][node]
    __shared__ float ws[128][64];   // W feature chunk
    int tid = threadIdx.x;
    int nb = blockIdx.x * 64;
    const float4* h4 = (const float4*)h;
#pragma unroll
    for (int r = 0; r < 8; ++r) {
        int idx = r * 256 + tid;           // 0..2047
        int ni = idx >> 5;                 // node within tile
        int k4 = idx & 31;                 // float4 index along k
        int node = nb + ni;
        float4 v = make_float4(0.f, 0.f, 0.f, 0.f);
        if (node < n) v = h4[(size_t)node * 32 + k4];
        hs[k4 * 4 + 0][ni] = v.x; hs[k4 * 4 + 1][ni] = v.y;
        hs[k4 * 4 + 2][ni] = v.z; hs[k4 * 4 + 3][ni] = v.w;
    }
    int fg = tid & 15, ng = tid >> 4;
    const float4* w4 = (const float4*)W;
    for (int c = 0; c < 2; ++c) {
        if (c) __syncthreads();
#pragma unroll
        for (int r = 0; r < 8; ++r) {
            int idx = r * 256 + tid;       // 0..2047
            int k = idx >> 4, f4 = idx & 15;
            *((float4*)&ws[k][f4 * 4]) = w4[k * 32 + c * 16 + f4];
        }
        __syncthreads();
        float acc[4][4] = {{0.f}};
#pragma unroll 8
        for (int k = 0; k < 128; ++k) {
            float2 a0 = *((const float2*)&hs[k][ng * 4]);
            float2 a1 = *((const float2*)&hs[k][ng * 4 + 2]);
            float4 w = *((const float4*)&ws[k][fg * 4]);
            float av[4] = {a0.x, a0.y, a1.x, a1.y};
            float wv[4] = {w.x, w.y, w.z, w.w};
#pragma unroll
            for (int i = 0; i < 4; ++i)
#pragma unroll
                for (int j = 0; j < 4; ++j)
                    acc[i][j] += av[i] * wv[j];
        }
#pragma unroll
        for (int i = 0; i < 4; ++i) {
            int node = nb + ng * 4 + i;
            if (node < n) {
                float dv = dinv[node];
                *((float4*)&out[(size_t)node * 128 + c * 64 + fg * 4]) =
                    make_float4(acc[i][0] * dv, acc[i][1] * dv, acc[i][2] * dv, acc[i][3] * dv);
            }
        }
    }
}

// ---------------- aggregation: out[i] = dinv[i]*(t'[i] + sum_{s in N(i)} t'[s]) + b ----
// t' rows already scaled by dinv[src]. One wave per node, lane = feature pair.
// Edge loop unrolled x4 to raise memory-level parallelism (latency-bound gather).

__global__ __launch_bounds__(256) void k_agg(const float* __restrict__ t, const int* __restrict__ offs,
                                             const int* __restrict__ csr, const float* __restrict__ dinv,
                                             const float* __restrict__ bias, float* __restrict__ out, int n) {
    int lane = threadIdx.x & 63;
    int node = blockIdx.x * 4 + (threadIdx.x >> 6);
    if (node >= n) return;
    const float2* t2 = (const float2*)t;
    float2 v = t2[(size_t)node * 64 + lane];   // self-loop: t'[node] = t[node]*dinv[node]
    float ax = v.x, ay = v.y;
    int e0 = offs[node], e1 = offs[node + 1];
    int e = e0;
    for (; e + 4 <= e1; e += 4) {
        int s0 = csr[e + 0], s1 = csr[e + 1], s2 = csr[e + 2], s3 = csr[e + 3];
        float2 u0 = t2[(size_t)s0 * 64 + lane];
        float2 u1 = t2[(size_t)s1 * 64 + lane];
        float2 u2 = t2[(size_t)s2 * 64 + lane];
        float2 u3 = t2[(size_t)s3 * 64 + lane];
        ax += (u0.x + u1.x) + (u2.x + u3.x);
        ay += (u0.y + u1.y) + (u2.y + u3.y);
    }
    for (; e < e1; ++e) {
        int s = csr[e];
        float2 u = t2[(size_t)s * 64 + lane];
        ax += u.x; ay += u.y;
    }
    float di = dinv[node];
    float2 b = ((const float2*)bias)[lane];
    ((float2*)out)[(size_t)node * 64 + lane] = make_float2(ax * di + b.x, ay * di + b.y);
}

// ---------------- BN ----------------

__global__ void k_bn_stats128(const float* __restrict__ v, float* __restrict__ S,
                              float* __restrict__ SS, int n) {
    int j = threadIdx.x;  // 128 threads
    int per = (n + gridDim.x - 1) / gridDim.x;
    int start = blockIdx.x * per;
    int end = min(start + per, n);
    float s = 0.f, ss = 0.f;
    for (int i = start; i < end; ++i) {
        float x = v[(size_t)i * 128 + j];
        s += x; ss += x * x;
    }
    atomicAdd(&S[j], s);
    atomicAdd(&SS[j], ss);
}

__global__ void k_bn_stats32(const float* __restrict__ v, float* __restrict__ S,
                             float* __restrict__ SS, int n) {
    int j = threadIdx.x & 31, sub = threadIdx.x >> 5;
    int per = (n + gridDim.x - 1) / gridDim.x;
    int start = blockIdx.x * per;
    int end = min(start + per, n);
    float s = 0.f, ss = 0.f;
    for (int i = start + sub; i < end; i += 4) {
        float x = v[(size_t)i * 32 + j];
        s += x; ss += x * x;
    }
    atomicAdd(&S[j], s);
    atomicAdd(&SS[j], ss);
}

__global__ void k_bn_finalize(const float* __restrict__ S, const float* __restrict__ SS,
                              const float* __restrict__ g, const float* __restrict__ bt,
                              float* __restrict__ A, float* __restrict__ C, int n, int hid) {
    int j = threadIdx.x;
    if (j >= hid) return;
    float mu = S[j] / (float)n;
    float var = SS[j] / (float)n - mu * mu;
    float inv = rsqrtf(var + EPS);
    A[j] = g[j] * inv;
    C[j] = bt[j] - mu * g[j] * inv;
}

// h[i] = relu(agg[i]*A + C) + h[i]
__global__ void k_bn_apply_res(const float* __restrict__ agg, const float* __restrict__ A,
                               const float* __restrict__ C, float* __restrict__ h, int total) {
    int i = blockIdx.x * 256 + threadIdx.x;
    if (i < total) {
        int j = i & 127;
        float v = agg[i] * A[j] + C[j];
        h[i] += fmaxf(v, 0.f);
    }
}

// ---------------- head GEMM: tf = h @ Wf1 + bf1 (128 -> 32) ----------------

__global__ __launch_bounds__(256) void k_gemmf(const float* __restrict__ h, const float* __restrict__ W,
                                               const float* __restrict__ bias, float* __restrict__ out, int n) {
    __shared__ float hs[128][66];
    __shared__ float ws[128][32];
    int tid = threadIdx.x;
    int nb = blockIdx.x * 64;
    const float4* h4 = (const float4*)h;
#pragma unroll
    for (int r = 0; r < 8; ++r) {
        int idx = r * 256 + tid;
        int ni = idx >> 5, k4 = idx & 31;
        int node = nb + ni;
        float4 v = make_float4(0.f, 0.f, 0.f, 0.f);
        if (node < n) v = h4[(size_t)node * 32 + k4];
        hs[k4 * 4 + 0][ni] = v.x; hs[k4 * 4 + 1][ni] = v.y;
        hs[k4 * 4 + 2][ni] = v.z; hs[k4 * 4 + 3][ni] = v.w;
    }
    const float4* w4 = (const float4*)W;
#pragma unroll
    for (int r = 0; r < 4; ++r) {
        int idx = r * 256 + tid;   // 0..1023
        int k = idx >> 3, f4 = idx & 7;
        *((float4*)&ws[k][f4 * 4]) = w4[k * 8 + f4];
    }
    __syncthreads();
    int fg = tid & 7, ng = tid >> 3;
    float acc[2][4] = {{0.f}};
#pragma unroll 8
    for (int k = 0; k < 128; ++k) {
        float2 a = *((const float2*)&hs[k][ng * 2]);
        float4 w = *((const float4*)&ws[k][fg * 4]);
        acc[0][0] += a.x * w.x; acc[0][1] += a.x * w.y; acc[0][2] += a.x * w.z; acc[0][3] += a.x * w.w;
        acc[1][0] += a.y * w.x; acc[1][1] += a.y * w.y; acc[1][2] += a.y * w.z; acc[1][3] += a.y * w.w;
    }
    float4 bb = *((const float4*)&bias[fg * 4]);
#pragma unroll
    for (int i = 0; i < 2; ++i) {
        int node = nb + ng * 2 + i;
        if (node < n)
            *((float4*)&out[(size_t)node * 32 + fg * 4]) =
                make_float4(acc[i][0] + bb.x, acc[i][1] + bb.y, acc[i][2] + bb.z, acc[i][3] + bb.w);
    }
}

// ---------------- final: out = tanh(relu(bn(tf)) @ Wf2 + bf2) ----------------

__global__ void k_final(const float* __restrict__ tf, const float* __restrict__ A,
                        const float* __restrict__ C, const float* __restrict__ Wf2,
                        const float* __restrict__ bf2, float* __restrict__ out, int n) {
    int node = blockIdx.x * 256 + threadIdx.x;
    if (node >= n) return;
    float o0 = bf2[0], o1 = bf2[1];
    const float4* t4 = (const float4*)(tf + (size_t)node * 32);
#pragma unroll
    for (int q = 0; q < 8; ++q) {
        float4 v = t4[q];
        float vv[4] = {v.x, v.y, v.z, v.w};
#pragma unroll
        for (int r = 0; r < 4; ++r) {
            int j = q * 4 + r;
            float f = fmaxf(vv[r] * A[j] + C[j], 0.f);
            o0 += f * Wf2[2 * j];
            o1 += f * Wf2[2 * j + 1];
        }
    }
    out[2 * node] = tanhf(o0);
    out[2 * node + 1] = tanhf(o1);
}

// ---------------- launch ----------------

extern "C" void kernel_launch(void* const* d_in, const int* in_sizes, int n_in,
                              void* d_out, int out_size, void* d_ws, size_t ws_size,
                              hipStream_t stream) {
    const float* x   = (const float*)d_in[0];
    const int*   ei  = (const int*)d_in[1];
    const float* We  = (const float*)d_in[2];
    const float* be  = (const float*)d_in[3];
    const float* W1  = (const float*)d_in[4];
    const float* b1  = (const float*)d_in[5];
    const float* g1  = (const float*)d_in[6];
    const float* bt1 = (const float*)d_in[7];
    const float* W2  = (const float*)d_in[8];
    const float* b2  = (const float*)d_in[9];
    const float* g2  = (const float*)d_in[10];
    const float* bt2 = (const float*)d_in[11];
    const float* W3  = (const float*)d_in[12];
    const float* b3  = (const float*)d_in[13];
    const float* g3  = (const float*)d_in[14];
    const float* bt3 = (const float*)d_in[15];
    const float* Wf1 = (const float*)d_in[16];
    const float* bf1 = (const float*)d_in[17];
    const float* gf  = (const float*)d_in[18];
    const float* btf = (const float*)d_in[19];
    const float* Wf2 = (const float*)d_in[20];
    const float* bf2 = (const float*)d_in[21];
    float* out = (float*)d_out;

    const int n = in_sizes[0] / 2;      // x is [N,2]
    const int e = in_sizes[1] / 2;      // edge_index is [2,E]
    const int* srcp = ei;
    const int* dstp = ei + e;

    char* p = (char*)d_ws;
    auto alloc = [&](size_t bytes) { void* r = (void*)p; p += (bytes + 255) & ~(size_t)255; return r; };
    int*   degc   = (int*)alloc((size_t)n * 4);
    int*   offs   = (int*)alloc((size_t)(n + 1) * 4);
    int*   cursor = (int*)alloc((size_t)n * 4);
    int*   csr    = (int*)alloc((size_t)e * 4);
    float* dinv   = (float*)alloc((size_t)n * 4);
    float* h      = (float*)alloc((size_t)n * HID * 4);
    float* t      = (float*)alloc((size_t)n * HID * 4);
    float* agg    = (float*)alloc((size_t)n * HID * 4);
    float* bnS    = (float*)alloc(HID * 4);
    float* bnSS   = (float*)alloc(HID * 4);
    float* bnA    = (float*)alloc(HID * 4);
    float* bnC    = (float*)alloc(HID * 4);
    float* tf     = t;  // alias: t is dead by head stage

    hipMemsetAsync(degc, 0, (size_t)n * 4, stream);
    k_count_deg<<<(e + 255) / 256, 256, 0, stream>>>(dstp, degc, e);
    k_dinv<<<(n + 255) / 256, 256, 0, stream>>>(degc, dinv, n);
    k_scan<<<1, 1024, 0, stream>>>(degc, offs, n);
    k_copy<<<(n + 255) / 256, 256, 0, stream>>>(offs, cursor, n);
    k_fill<<<(e + 255) / 256, 256, 0, stream>>>(srcp, dstp, cursor, csr, e);
    k_embed<<<(n * HID + 255) / 256, 256, 0, stream>>>(x, We, be, h, n);

    const float* Wl[3]  = {W1, W2, W3};
    const float* bl[3]  = {b1, b2, b3};
    const float* gl[3]  = {g1, g2, g3};
    const float* btl[3] = {bt1, bt2, bt3};
    for (int L = 0; L < 3; ++L) {
        k_gemm128<<<(n + 63) / 64, 256, 0, stream>>>(h, Wl[L], dinv, t, n);
        k_agg<<<(n + 3) / 4, 256, 0, stream>>>(t, offs, csr, dinv, bl[L], agg, n);
        hipMemsetAsync(bnS, 0, HID * 4, stream);
        hipMemsetAsync(bnSS, 0, HID * 4, stream);
        k_bn_stats128<<<512, 128, 0, stream>>>(agg, bnS, bnSS, n);
        k_bn_finalize<<<1, 128, 0, stream>>>(bnS, bnSS, gl[L], btl[L], bnA, bnC, n, 128);
        k_bn_apply_res<<<(n * HID + 255) / 256, 256, 0, stream>>>(agg, bnA, bnC, h, n * HID);
    }

    k_gemmf<<<(n + 63) / 64, 256, 0, stream>>>(h, Wf1, bf1, tf, n);
    hipMemsetAsync(bnS, 0, 32 * 4, stream);
    hipMemsetAsync(bnSS, 0, 32 * 4, stream);
    k_bn_stats32<<<512, 128, 0, stream>>>(tf, bnS, bnSS, n);
    k_bn_finalize<<<1, 32, 0, stream>>>(bnS, bnSS, gf, btf, bnA, bnC, n, 32);
    k_final<<<(n + 255) / 256, 256, 0, stream>>>(tf, bnA, bnC, Wf2, bf2, out, n);
}

// Round 3
// 1236.260 us; speedup vs baseline: 1.2462x; 1.1219x over previous
//
#include <hip/hip_runtime.h>
#include <math.h>

#define HID 128
#define EPS 1e-5f
#define SCAN_NB 128

// ---------------- graph preprocessing ----------------

__global__ void k_count_deg(const int* __restrict__ dst, int* __restrict__ degc, int e) {
    int i = blockIdx.x * 256 + threadIdx.x;
    if (i < e) atomicAdd(&degc[dst[i]], 1);
}

__global__ void k_dinv(const int* __restrict__ degc, float* __restrict__ dinv, int n) {
    int i = blockIdx.x * 256 + threadIdx.x;
    if (i < n) dinv[i] = rsqrtf((float)(degc[i] + 1));  // +1 self-loop; deg>=1 always
}

// ---- 3-phase exclusive scan of degc[n] -> offs[n+1] ----
// phase 1: per-block partial sums
__global__ __launch_bounds__(256) void k_scan_p1(const int* __restrict__ counts, int* __restrict__ part, int n) {
    __shared__ int lds[256];
    int b = blockIdx.x, tid = threadIdx.x;
    int chunk = (n + SCAN_NB - 1) / SCAN_NB;
    int cstart = b * chunk;
    int cend = min(cstart + chunk, n);
    int seg = (chunk + 255) >> 8;
    int start = cstart + tid * seg;
    int end = min(start + seg, cend);
    int s = 0;
    for (int i = start; i < end; ++i) s += counts[i];
    lds[tid] = s;
    __syncthreads();
    for (int off = 128; off > 0; off >>= 1) {
        if (tid < off) lds[tid] += lds[tid + off];
        __syncthreads();
    }
    if (tid == 0) part[b] = lds[0];
}

// phase 2: exclusive scan of part[SCAN_NB] (one block)
__global__ void k_scan_p2(int* __restrict__ part) {
    __shared__ int lds[SCAN_NB];
    int tid = threadIdx.x;  // SCAN_NB threads
    int v = part[tid];
    lds[tid] = v;
    __syncthreads();
    for (int off = 1; off < SCAN_NB; off <<= 1) {
        int u = (tid >= off) ? lds[tid - off] : 0;
        __syncthreads();
        lds[tid] += u;
        __syncthreads();
    }
    part[tid] = lds[tid] - v;  // exclusive
}

// phase 3: per-block local exclusive scan + base; offs[n] = e
__global__ __launch_bounds__(256) void k_scan_p3(const int* __restrict__ counts, const int* __restrict__ part,
                                                 int* __restrict__ offs, int n, int etot) {
    __shared__ int lds[256];
    int b = blockIdx.x, tid = threadIdx.x;
    int chunk = (n + SCAN_NB - 1) / SCAN_NB;
    int cstart = b * chunk;
    int cend = min(cstart + chunk, n);
    int seg = (chunk + 255) >> 8;
    int start = cstart + tid * seg;
    int end = min(start + seg, cend);
    int s = 0;
    for (int i = start; i < end; ++i) s += counts[i];
    lds[tid] = s;
    __syncthreads();
    for (int off = 1; off < 256; off <<= 1) {
        int u = (tid >= off) ? lds[tid - off] : 0;
        __syncthreads();
        lds[tid] += u;
        __syncthreads();
    }
    int prefix = part[b] + lds[tid] - s;  // exclusive within chunk + block base
    for (int i = start; i < end; ++i) { offs[i] = prefix; prefix += counts[i]; }
    if (b == 0 && tid == 0) offs[n] = etot;
}

__global__ void k_copy(const int* __restrict__ a, int* __restrict__ b, int n) {
    int i = blockIdx.x * 256 + threadIdx.x;
    if (i < n) b[i] = a[i];
}

__global__ void k_fill(const int* __restrict__ src, const int* __restrict__ dst,
                       int* __restrict__ cursor, int* __restrict__ csr, int e) {
    int i = blockIdx.x * 256 + threadIdx.x;
    if (i < e) {
        int d = dst[i];
        int pos = atomicAdd(&cursor[d], 1);
        csr[pos] = src[i];
    }
}

// ---------------- embed: h = relu(x @ We + be), x is [N,2] ----------------

__global__ void k_embed(const float* __restrict__ x, const float* __restrict__ We,
                        const float* __restrict__ be, float* __restrict__ h, int n) {
    int i = blockIdx.x * 256 + threadIdx.x;
    if (i >= n * HID) return;
    int node = i >> 7, j = i & 127;
    float v = x[2 * node] * We[j] + x[2 * node + 1] * We[HID + j] + be[j];
    h[i] = fmaxf(v, 0.f);
}

// ---------------- GEMM: t'[n][j] = dinv[n] * sum_k h[n][k] * W[k][j], 128x128 ---------

__global__ __launch_bounds__(256) void k_gemm128(const float* __restrict__ h, const float* __restrict__ W,
                                                 const float* __restrict__ dinv,
                                                 float* __restrict__ out, int n) {
    __shared__ float hs[128][66];
    __shared__ float ws[128][64];
    int tid = threadIdx.x;
    int nb = blockIdx.x * 64;
    const float4* h4 = (const float4*)h;
#pragma unroll
    for (int r = 0; r < 8; ++r) {
        int idx = r * 256 + tid;
        int ni = idx >> 5;
        int k4 = idx & 31;
        int node = nb + ni;
        float4 v = make_float4(0.f, 0.f, 0.f, 0.f);
        if (node < n) v = h4[(size_t)node * 32 + k4];
        hs[k4 * 4 + 0][ni] = v.x; hs[k4 * 4 + 1][ni] = v.y;
        hs[k4 * 4 + 2][ni] = v.z; hs[k4 * 4 + 3][ni] = v.w;
    }
    int fg = tid & 15, ng = tid >> 4;
    const float4* w4 = (const float4*)W;
    for (int c = 0; c < 2; ++c) {
        if (c) __syncthreads();
#pragma unroll
        for (int r = 0; r < 8; ++r) {
            int idx = r * 256 + tid;
            int k = idx >> 4, f4 = idx & 15;
            *((float4*)&ws[k][f4 * 4]) = w4[k * 32 + c * 16 + f4];
        }
        __syncthreads();
        float acc[4][4] = {{0.f}};
#pragma unroll 8
        for (int k = 0; k < 128; ++k) {
            float2 a0 = *((const float2*)&hs[k][ng * 4]);
            float2 a1 = *((const float2*)&hs[k][ng * 4 + 2]);
            float4 w = *((const float4*)&ws[k][fg * 4]);
            float av[4] = {a0.x, a0.y, a1.x, a1.y};
            float wv[4] = {w.x, w.y, w.z, w.w};
#pragma unroll
            for (int i = 0; i < 4; ++i)
#pragma unroll
                for (int j = 0; j < 4; ++j)
                    acc[i][j] += av[i] * wv[j];
        }
#pragma unroll
        for (int i = 0; i < 4; ++i) {
            int node = nb + ng * 4 + i;
            if (node < n) {
                float dv = dinv[node];
                *((float4*)&out[(size_t)node * 128 + c * 64 + fg * 4]) =
                    make_float4(acc[i][0] * dv, acc[i][1] * dv, acc[i][2] * dv, acc[i][3] * dv);
            }
        }
    }
}

// ---------------- aggregation: out[i] = dinv[i]*(t'[i] + sum_{s in N(i)} t'[s]) + b ----
// One wave per node, lane = feature pair. Edge loop unrolled x8 for MLP.

__global__ __launch_bounds__(256) void k_agg(const float* __restrict__ t, const int* __restrict__ offs,
                                             const int* __restrict__ csr, const float* __restrict__ dinv,
                                             const float* __restrict__ bias, float* __restrict__ out, int n) {
    int lane = threadIdx.x & 63;
    int node = blockIdx.x * 4 + (threadIdx.x >> 6);
    if (node >= n) return;
    const float2* t2 = (const float2*)t;
    float2 v = t2[(size_t)node * 64 + lane];
    float ax = v.x, ay = v.y;
    int e0 = offs[node], e1 = offs[node + 1];
    int e = e0;
    for (; e + 8 <= e1; e += 8) {
        int s0 = csr[e + 0], s1 = csr[e + 1], s2 = csr[e + 2], s3 = csr[e + 3];
        int s4 = csr[e + 4], s5 = csr[e + 5], s6 = csr[e + 6], s7 = csr[e + 7];
        float2 u0 = t2[(size_t)s0 * 64 + lane];
        float2 u1 = t2[(size_t)s1 * 64 + lane];
        float2 u2 = t2[(size_t)s2 * 64 + lane];
        float2 u3 = t2[(size_t)s3 * 64 + lane];
        float2 u4 = t2[(size_t)s4 * 64 + lane];
        float2 u5 = t2[(size_t)s5 * 64 + lane];
        float2 u6 = t2[(size_t)s6 * 64 + lane];
        float2 u7 = t2[(size_t)s7 * 64 + lane];
        ax += ((u0.x + u1.x) + (u2.x + u3.x)) + ((u4.x + u5.x) + (u6.x + u7.x));
        ay += ((u0.y + u1.y) + (u2.y + u3.y)) + ((u4.y + u5.y) + (u6.y + u7.y));
    }
    if (e + 4 <= e1) {
        int s0 = csr[e + 0], s1 = csr[e + 1], s2 = csr[e + 2], s3 = csr[e + 3];
        float2 u0 = t2[(size_t)s0 * 64 + lane];
        float2 u1 = t2[(size_t)s1 * 64 + lane];
        float2 u2 = t2[(size_t)s2 * 64 + lane];
        float2 u3 = t2[(size_t)s3 * 64 + lane];
        ax += (u0.x + u1.x) + (u2.x + u3.x);
        ay += (u0.y + u1.y) + (u2.y + u3.y);
        e += 4;
    }
    for (; e < e1; ++e) {
        int s = csr[e];
        float2 u = t2[(size_t)s * 64 + lane];
        ax += u.x; ay += u.y;
    }
    float di = dinv[node];
    float2 b = ((const float2*)bias)[lane];
    ((float2*)out)[(size_t)node * 64 + lane] = make_float2(ax * di + b.x, ay * di + b.y);
}

// ---------------- BN ----------------

__global__ void k_bn_stats128(const float* __restrict__ v, float* __restrict__ S,
                              float* __restrict__ SS, int n) {
    int j = threadIdx.x;  // 128 threads
    int per = (n + gridDim.x - 1) / gridDim.x;
    int start = blockIdx.x * per;
    int end = min(start + per, n);
    float s = 0.f, ss = 0.f;
    for (int i = start; i < end; ++i) {
        float x = v[(size_t)i * 128 + j];
        s += x; ss += x * x;
    }
    atomicAdd(&S[j], s);
    atomicAdd(&SS[j], ss);
}

__global__ void k_bn_stats32(const float* __restrict__ v, float* __restrict__ S,
                             float* __restrict__ SS, int n) {
    int j = threadIdx.x & 31, sub = threadIdx.x >> 5;
    int per = (n + gridDim.x - 1) / gridDim.x;
    int start = blockIdx.x * per;
    int end = min(start + per, n);
    float s = 0.f, ss = 0.f;
    for (int i = start + sub; i < end; i += 4) {
        float x = v[(size_t)i * 32 + j];
        s += x; ss += x * x;
    }
    atomicAdd(&S[j], s);
    atomicAdd(&SS[j], ss);
}

__global__ void k_bn_finalize(const float* __restrict__ S, const float* __restrict__ SS,
                              const float* __restrict__ g, const float* __restrict__ bt,
                              float* __restrict__ A, float* __restrict__ C, int n, int hid) {
    int j = threadIdx.x;
    if (j >= hid) return;
    float mu = S[j] / (float)n;
    float var = SS[j] / (float)n - mu * mu;
    float inv = rsqrtf(var + EPS);
    A[j] = g[j] * inv;
    C[j] = bt[j] - mu * g[j] * inv;
}

// h[i] = relu(agg[i]*A + C) + h[i]
__global__ void k_bn_apply_res(const float* __restrict__ agg, const float* __restrict__ A,
                               const float* __restrict__ C, float* __restrict__ h, int total) {
    int i = blockIdx.x * 256 + threadIdx.x;
    if (i < total) {
        int j = i & 127;
        float v = agg[i] * A[j] + C[j];
        h[i] += fmaxf(v, 0.f);
    }
}

// ---------------- head GEMM: tf = h @ Wf1 + bf1 (128 -> 32) ----------------

__global__ __launch_bounds__(256) void k_gemmf(const float* __restrict__ h, const float* __restrict__ W,
                                               const float* __restrict__ bias, float* __restrict__ out, int n) {
    __shared__ float hs[128][66];
    __shared__ float ws[128][32];
    int tid = threadIdx.x;
    int nb = blockIdx.x * 64;
    const float4* h4 = (const float4*)h;
#pragma unroll
    for (int r = 0; r < 8; ++r) {
        int idx = r * 256 + tid;
        int ni = idx >> 5, k4 = idx & 31;
        int node = nb + ni;
        float4 v = make_float4(0.f, 0.f, 0.f, 0.f);
        if (node < n) v = h4[(size_t)node * 32 + k4];
        hs[k4 * 4 + 0][ni] = v.x; hs[k4 * 4 + 1][ni] = v.y;
        hs[k4 * 4 + 2][ni] = v.z; hs[k4 * 4 + 3][ni] = v.w;
    }
    const float4* w4 = (const float4*)W;
#pragma unroll
    for (int r = 0; r < 4; ++r) {
        int idx = r * 256 + tid;
        int k = idx >> 3, f4 = idx & 7;
        *((float4*)&ws[k][f4 * 4]) = w4[k * 8 + f4];
    }
    __syncthreads();
    int fg = tid & 7, ng = tid >> 3;
    float acc[2][4] = {{0.f}};
#pragma unroll 8
    for (int k = 0; k < 128; ++k) {
        float2 a = *((const float2*)&hs[k][ng * 2]);
        float4 w = *((const float4*)&ws[k][fg * 4]);
        acc[0][0] += a.x * w.x; acc[0][1] += a.x * w.y; acc[0][2] += a.x * w.z; acc[0][3] += a.x * w.w;
        acc[1][0] += a.y * w.x; acc[1][1] += a.y * w.y; acc[1][2] += a.y * w.z; acc[1][3] += a.y * w.w;
    }
    float4 bb = *((const float4*)&bias[fg * 4]);
#pragma unroll
    for (int i = 0; i < 2; ++i) {
        int node = nb + ng * 2 + i;
        if (node < n)
            *((float4*)&out[(size_t)node * 32 + fg * 4]) =
                make_float4(acc[i][0] + bb.x, acc[i][1] + bb.y, acc[i][2] + bb.z, acc[i][3] + bb.w);
    }
}

// ---------------- final: out = tanh(relu(bn(tf)) @ Wf2 + bf2) ----------------

__global__ void k_final(const float* __restrict__ tf, const float* __restrict__ A,
                        const float* __restrict__ C, const float* __restrict__ Wf2,
                        const float* __restrict__ bf2, float* __restrict__ out, int n) {
    int node = blockIdx.x * 256 + threadIdx.x;
    if (node >= n) return;
    float o0 = bf2[0], o1 = bf2[1];
    const float4* t4 = (const float4*)(tf + (size_t)node * 32);
#pragma unroll
    for (int q = 0; q < 8; ++q) {
        float4 v = t4[q];
        float vv[4] = {v.x, v.y, v.z, v.w};
#pragma unroll
        for (int r = 0; r < 4; ++r) {
            int j = q * 4 + r;
            float f = fmaxf(vv[r] * A[j] + C[j], 0.f);
            o0 += f * Wf2[2 * j];
            o1 += f * Wf2[2 * j + 1];
        }
    }
    out[2 * node] = tanhf(o0);
    out[2 * node + 1] = tanhf(o1);
}

// ---------------- launch ----------------

extern "C" void kernel_launch(void* const* d_in, const int* in_sizes, int n_in,
                              void* d_out, int out_size, void* d_ws, size_t ws_size,
                              hipStream_t stream) {
    const float* x   = (const float*)d_in[0];
    const int*   ei  = (const int*)d_in[1];
    const float* We  = (const float*)d_in[2];
    const float* be  = (const float*)d_in[3];
    const float* W1  = (const float*)d_in[4];
    const float* b1  = (const float*)d_in[5];
    const float* g1  = (const float*)d_in[6];
    const float* bt1 = (const float*)d_in[7];
    const float* W2  = (const float*)d_in[8];
    const float* b2  = (const float*)d_in[9];
    const float* g2  = (const float*)d_in[10];
    const float* bt2 = (const float*)d_in[11];
    const float* W3  = (const float*)d_in[12];
    const float* b3  = (const float*)d_in[13];
    const float* g3  = (const float*)d_in[14];
    const float* bt3 = (const float*)d_in[15];
    const float* Wf1 = (const float*)d_in[16];
    const float* bf1 = (const float*)d_in[17];
    const float* gf  = (const float*)d_in[18];
    const float* btf = (const float*)d_in[19];
    const float* Wf2 = (const float*)d_in[20];
    const float* bf2 = (const float*)d_in[21];
    float* out = (float*)d_out;

    const int n = in_sizes[0] / 2;      // x is [N,2]
    const int e = in_sizes[1] / 2;      // edge_index is [2,E]
    const int* srcp = ei;
    const int* dstp = ei + e;

    char* p = (char*)d_ws;
    auto alloc = [&](size_t bytes) { void* r = (void*)p; p += (bytes + 255) & ~(size_t)255; return r; };
    int*   degc   = (int*)alloc((size_t)n * 4);
    int*   offs   = (int*)alloc((size_t)(n + 1) * 4);
    int*   cursor = (int*)alloc((size_t)n * 4);
    int*   csr    = (int*)alloc((size_t)e * 4);
    int*   part   = (int*)alloc(SCAN_NB * 4);
    float* dinv   = (float*)alloc((size_t)n * 4);
    float* h      = (float*)alloc((size_t)n * HID * 4);
    float* t      = (float*)alloc((size_t)n * HID * 4);
    float* agg    = (float*)alloc((size_t)n * HID * 4);
    float* bnS    = (float*)alloc(HID * 4);
    float* bnSS   = (float*)alloc(HID * 4);
    float* bnA    = (float*)alloc(HID * 4);
    float* bnC    = (float*)alloc(HID * 4);
    float* tf     = t;  // alias: t is dead by head stage

    hipMemsetAsync(degc, 0, (size_t)n * 4, stream);
    k_count_deg<<<(e + 255) / 256, 256, 0, stream>>>(dstp, degc, e);
    k_dinv<<<(n + 255) / 256, 256, 0, stream>>>(degc, dinv, n);
    k_scan_p1<<<SCAN_NB, 256, 0, stream>>>(degc, part, n);
    k_scan_p2<<<1, SCAN_NB, 0, stream>>>(part);
    k_scan_p3<<<SCAN_NB, 256, 0, stream>>>(degc, part, offs, n, e);
    k_copy<<<(n + 255) / 256, 256, 0, stream>>>(offs, cursor, n);
    k_fill<<<(e + 255) / 256, 256, 0, stream>>>(srcp, dstp, cursor, csr, e);
    k_embed<<<(n * HID + 255) / 256, 256, 0, stream>>>(x, We, be, h, n);

    const float* Wl[3]  = {W1, W2, W3};
    const float* bl[3]  = {b1, b2, b3};
    const float* gl[3]  = {g1, g2, g3};
    const float* btl[3] = {bt1, bt2, bt3};
    for (int L = 0; L < 3; ++L) {
        k_gemm128<<<(n + 63) / 64, 256, 0, stream>>>(h, Wl[L], dinv, t, n);
        k_agg<<<(n + 3) / 4, 256, 0, stream>>>(t, offs, csr, dinv, bl[L], agg, n);
        hipMemsetAsync(bnS, 0, HID * 4, stream);
        hipMemsetAsync(bnSS, 0, HID * 4, stream);
        k_bn_stats128<<<512, 128, 0, stream>>>(agg, bnS, bnSS, n);
        k_bn_finalize<<<1, 128, 0, stream>>>(bnS, bnSS, gl[L], btl[L], bnA, bnC, n, 128);
        k_bn_apply_res<<<(n * HID + 255) / 256, 256, 0, stream>>>(agg, bnA, bnC, h, n * HID);
    }

    k_gemmf<<<(n + 63) / 64, 256, 0, stream>>>(h, Wf1, bf1, tf, n);
    hipMemsetAsync(bnS, 0, 32 * 4, stream);
    hipMemsetAsync(bnSS, 0, 32 * 4, stream);
    k_bn_stats32<<<512, 128, 0, stream>>>(tf, bnS, bnSS, n);
    k_bn_finalize<<<1, 32, 0, stream>>>(bnS, bnSS, gf, btf, bnA, bnC, n, 32);
    k_final<<<(n + 255) / 256, 256, 0, stream>>>(tf, bnA, bnC, Wf2, bf2, out, n);
}